// Round 2
// baseline (3837.093 us; speedup 1.0000x reference)
//
#include <hip/hip_runtime.h>
#include <hip/hip_bf16.h>
#include <math.h>

typedef __hip_bfloat16 bf16;

// ---------- bf16 helpers (bit-level, RNE pack) ----------
__device__ __forceinline__ float bfbits2f(unsigned int u) {
    union { unsigned int i; float f; } c; c.i = u << 16; return c.f;
}
__device__ __forceinline__ float b2f(const bf16 v) {
    return __bfloat162float(v);
}
__device__ __forceinline__ unsigned short f2bbits(float f) {
    unsigned int x = __float_as_uint(f);
    x += 0x7fffu + ((x >> 16) & 1u);   // round-to-nearest-even
    return (unsigned short)(x >> 16);
}
__device__ __forceinline__ void unpack8(const uint4 v, float* f) {
    f[0]=bfbits2f(v.x & 0xffffu); f[1]=bfbits2f(v.x >> 16);
    f[2]=bfbits2f(v.y & 0xffffu); f[3]=bfbits2f(v.y >> 16);
    f[4]=bfbits2f(v.z & 0xffffu); f[5]=bfbits2f(v.z >> 16);
    f[6]=bfbits2f(v.w & 0xffffu); f[7]=bfbits2f(v.w >> 16);
}

// input loaders (fp32 global activations vs bf16 internal activations)
__device__ __forceinline__ float ldx(const float* p) { return *p; }
__device__ __forceinline__ float ldx(const bf16* p)  { return b2f(*p); }

// ---------- tiny utility kernels ----------
__global__ void zero_k(float* p, int n) {
    int e = blockIdx.x * 256 + threadIdx.x;
    if (e < n) p[e] = 0.f;
}

// dec_W2 [576,3] fp32 -> Wf [3][576] fp32 (transposed so inner loop is uniform/scalar)
__global__ void wcvt_k(const float* __restrict__ W, float* __restrict__ Wf) {
    int e = blockIdx.x * 256 + threadIdx.x;
    if (e < 1728) {
        int k = e / 3, co = e - k * 3;
        Wf[co * 576 + k] = W[e];
    }
}

// ---------- spiral conv: out[b,v,co] = sum_{s,ci} x[b, idx[v,s], ci] * W[s*CIN+ci, co] + bias ----------
template<typename XT, int CIN, int COUT, int NCO, int TV, bool ELU>
__global__ __launch_bounds__(256) void conv_k(
    const XT* __restrict__ x, const int* __restrict__ idx,
    const float* __restrict__ W, const float* __restrict__ bias,
    bf16* __restrict__ out, const int V, const int Vin)
{
    constexpr int S = 9, K = S * CIN;
    constexpr int COLS = COUT / NCO;      // threads along output channels
    constexpr int NG   = 256 / COLS;      // vertex groups per block
    constexpr int NV   = TV / NG;         // vertices per thread
    static_assert(256 % COLS == 0 && TV % NG == 0 && COUT % NCO == 0, "cfg");
    __shared__ __align__(16) float xs[TV][K];

    const int b  = blockIdx.y;
    const int v0 = blockIdx.x * TV;
    const int t  = threadIdx.x;

    // stage gathered rows into LDS (fp32)
    for (int e = t; e < TV * K; e += 256) {
        const int v = e / K, k = e - v * K;
        const int s = k / CIN, ci = k - s * CIN;
        const int src = idx[(v0 + v) * 9 + s];
        xs[v][k] = ldx(x + ((size_t)b * Vin + src) * CIN + ci);
    }
    __syncthreads();

    const int c   = t % COLS;
    const int vg  = t / COLS;
    const int co0 = c * NCO;
    const int vb  = vg * NV;

    float acc[NV][NCO];
    #pragma unroll
    for (int i = 0; i < NV; ++i)
        #pragma unroll
        for (int n = 0; n < NCO; ++n)
            acc[i][n] = bias[co0 + n];

    if constexpr ((K % 4) == 0) {
        for (int k = 0; k < K; k += 4) {
            float w[4][NCO];
            #pragma unroll
            for (int u = 0; u < 4; ++u) {
                if constexpr (NCO == 4) {
                    const float4 wv = *(const float4*)(W + (size_t)(k + u) * COUT + co0);
                    w[u][0]=wv.x; w[u][1]=wv.y; w[u][2]=wv.z; w[u][3]=wv.w;
                } else {
                    const float2 wv = *(const float2*)(W + (size_t)(k + u) * COUT + co0);
                    w[u][0]=wv.x; w[u][1]=wv.y;
                }
            }
            #pragma unroll
            for (int i = 0; i < NV; ++i) {
                const float4 xv = *(const float4*)(&xs[vb + i][k]);
                const float xa[4] = {xv.x, xv.y, xv.z, xv.w};
                #pragma unroll
                for (int u = 0; u < 4; ++u)
                    #pragma unroll
                    for (int n = 0; n < NCO; ++n)
                        acc[i][n] += xa[u] * w[u][n];
            }
        }
    } else {
        for (int k = 0; k < K; ++k) {
            float w[NCO];
            if constexpr (NCO == 4) {
                const float4 wv = *(const float4*)(W + (size_t)k * COUT + co0);
                w[0]=wv.x; w[1]=wv.y; w[2]=wv.z; w[3]=wv.w;
            } else {
                const float2 wv = *(const float2*)(W + (size_t)k * COUT + co0);
                w[0]=wv.x; w[1]=wv.y;
            }
            #pragma unroll
            for (int i = 0; i < NV; ++i) {
                const float xa = xs[vb + i][k];
                #pragma unroll
                for (int n = 0; n < NCO; ++n) acc[i][n] += xa * w[n];
            }
        }
    }

    #pragma unroll
    for (int i = 0; i < NV; ++i) {
        const size_t o = ((size_t)b * V + v0 + vb + i) * COUT + co0;
        unsigned short us[NCO];
        #pragma unroll
        for (int n = 0; n < NCO; ++n) {
            float a = acc[i][n];
            if constexpr (ELU) a = a > 0.f ? a : (__expf(a) - 1.f);
            us[n] = f2bbits(a);
        }
        if constexpr (NCO == 4) {
            uint2 st; st.x = us[0] | ((unsigned)us[1] << 16);
            st.y = us[2] | ((unsigned)us[3] << 16);
            *(uint2*)(out + o) = st;
        } else {
            unsigned int st = us[0] | ((unsigned)us[1] << 16);
            *(unsigned int*)(out + o) = st;
        }
    }
}

// ---------- pool: out[b,vo,c] = sum_k w[vo,k] * in[b, idx[vo,k], c] ----------
__global__ __launch_bounds__(256) void pool_k(
    const bf16* __restrict__ in, const int* __restrict__ idx,
    const float* __restrict__ w, bf16* __restrict__ out,
    const int Vout, const int Vin, const int C)
{
    const int nC8 = C >> 3;
    const long long total = (long long)16 * Vout * nC8;
    const long long gid = (long long)blockIdx.x * 256 + threadIdx.x;
    if (gid >= total) return;
    const int c8 = (int)(gid % nC8);
    const long long bv = gid / nC8;
    const int vo = (int)(bv % Vout);
    const int b  = (int)(bv / Vout);

    float r[8];
    #pragma unroll
    for (int u = 0; u < 8; ++u) r[u] = 0.f;
    #pragma unroll
    for (int jj = 0; jj < 3; ++jj) {
        const int src = idx[vo * 3 + jj];
        const float ww = w[vo * 3 + jj];
        const uint4 xv = *(const uint4*)(in + ((size_t)b * Vin + src) * C + c8 * 8);
        float f[8]; unpack8(xv, f);
        #pragma unroll
        for (int u = 0; u < 8; ++u) r[u] += ww * f[u];
    }
    uint4 st;
    st.x = f2bbits(r[0]) | ((unsigned)f2bbits(r[1]) << 16);
    st.y = f2bbits(r[2]) | ((unsigned)f2bbits(r[3]) << 16);
    st.z = f2bbits(r[4]) | ((unsigned)f2bbits(r[5]) << 16);
    st.w = f2bbits(r[6]) | ((unsigned)f2bbits(r[7]) << 16);
    *(uint4*)(out + ((size_t)b * Vout + vo) * C + c8 * 8) = st;
}

// ---------- z = F[16,81920] @ Wz[81920,256] (partial sums via atomics) ----------
__global__ __launch_bounds__(256) void zacc_k(
    const bf16* __restrict__ F, const float* __restrict__ Wz, float* __restrict__ zf)
{
    const int j  = threadIdx.x;          // output col
    const int i0 = blockIdx.x * 256;     // K-chunk
    float acc[16];
    #pragma unroll
    for (int b = 0; b < 16; ++b) acc[b] = 0.f;
    for (int i = i0; i < i0 + 256; i += 8) {
        float w[8];
        #pragma unroll
        for (int u = 0; u < 8; ++u) w[u] = Wz[(size_t)(i + u) * 256 + j];
        #pragma unroll
        for (int b = 0; b < 16; ++b) {
            const uint4 fv = *(const uint4*)(F + (size_t)b * 81920 + i);
            float f[8]; unpack8(fv, f);
            #pragma unroll
            for (int u = 0; u < 8; ++u) acc[b] += f[u] * w[u];
        }
    }
    #pragma unroll
    for (int b = 0; b < 16; ++b) atomicAdd(&zf[b * 256 + j], acc[b]);
}

// add bias, keep fp32 copy for decoder, emit fp32 z output
__global__ void zfin_k(float* __restrict__ zf, const float* __restrict__ bz,
                       float* __restrict__ outz)
{
    int e = blockIdx.x * 256 + threadIdx.x;  // 4096
    int j = e & 255;
    float v = zf[e] + bz[j];
    zf[e] = v;
    outz[e] = v;
}

// ---------- d[b,j] = sum_k z[b,k] * Wp[k,j] + bp[j], j in [0,81920) ----------
__global__ __launch_bounds__(256) void dproj_k(
    const float* __restrict__ zf, const float* __restrict__ Wp,
    const float* __restrict__ bp, bf16* __restrict__ d)
{
    __shared__ float zl[256][16];   // [k][b]
    const int t = threadIdx.x;
    #pragma unroll
    for (int b = 0; b < 16; ++b) zl[t][b] = zf[b * 256 + t];
    __syncthreads();
    const size_t j = (size_t)blockIdx.x * 256 + t;
    const float bpv = bp[j];
    float acc[16];
    #pragma unroll
    for (int b = 0; b < 16; ++b) acc[b] = bpv;
    for (int k = 0; k < 256; ++k) {
        const float w = Wp[(size_t)k * 81920 + j];
        #pragma unroll
        for (int b = 0; b < 16; ++b) acc[b] += zl[k][b] * w;
    }
    #pragma unroll
    for (int b = 0; b < 16; ++b) {
        union { unsigned short u; bf16 h; } c; c.u = f2bbits(acc[b]);
        d[(size_t)b * 81920 + j] = c.h;
    }
}

// ---------- final conv, COUT=3, no activation, fp32 output ----------
__global__ __launch_bounds__(256) void dec2_k(
    const bf16* __restrict__ x,    // [16,20480,64] bf16 intermediate
    const int* __restrict__ idx,   // [20480,9]
    const float* __restrict__ Wf,  // [3][576] fp32 (transposed)
    const float* __restrict__ bias,// [3]
    float* __restrict__ y)         // [16,20480,3] fp32
{
    const int gid = blockIdx.x * 256 + threadIdx.x;   // B*V0
    const int v = gid % 20480;
    const int b = gid / 20480;
    float a0 = bias[0], a1 = bias[1], a2 = bias[2];
    for (int s = 0; s < 9; ++s) {
        const int src = idx[v * 9 + s];
        const uint4* xr = (const uint4*)(x + ((size_t)b * 20480 + src) * 64);
        #pragma unroll
        for (int q = 0; q < 8; ++q) {
            const uint4 xv = xr[q];
            float f[8]; unpack8(xv, f);
            #pragma unroll
            for (int u = 0; u < 8; ++u) {
                const int k = s * 64 + q * 8 + u;   // uniform -> scalar loads
                a0 += f[u] * Wf[k];
                a1 += f[u] * Wf[576 + k];
                a2 += f[u] * Wf[1152 + k];
            }
        }
    }
    const size_t o = (size_t)gid * 3;
    y[o]     = a0;
    y[o + 1] = a1;
    y[o + 2] = a2;
}

extern "C" void kernel_launch(void* const* d_in, const int* in_sizes, int n_in,
                              void* d_out, int out_size, void* d_ws, size_t ws_size,
                              hipStream_t stream) {
    (void)in_sizes; (void)n_in; (void)out_size; (void)ws_size;
    const float* x     = (const float*)d_in[0];
    const float* encW0 = (const float*)d_in[1];
    const float* encb0 = (const float*)d_in[2];
    const float* encW1 = (const float*)d_in[3];
    const float* encb1 = (const float*)d_in[4];
    const float* encW2 = (const float*)d_in[5];
    const float* encb2 = (const float*)d_in[6];
    const float* Wz    = (const float*)d_in[7];
    const float* bz    = (const float*)d_in[8];
    const float* Wp    = (const float*)d_in[9];
    const float* bp    = (const float*)d_in[10];
    const float* decW0 = (const float*)d_in[11];
    const float* decb0 = (const float*)d_in[12];
    const float* decW1 = (const float*)d_in[13];
    const float* decb1 = (const float*)d_in[14];
    const float* decW2 = (const float*)d_in[15];
    const float* decb2 = (const float*)d_in[16];
    const float* dpw0  = (const float*)d_in[17];
    const float* dpw1  = (const float*)d_in[18];
    const float* dpw2  = (const float*)d_in[19];
    const float* upw0  = (const float*)d_in[20];
    const float* upw1  = (const float*)d_in[21];
    const float* upw2  = (const float*)d_in[22];
    const int* idx0    = (const int*)d_in[23];
    const int* idx1    = (const int*)d_in[24];
    const int* idx2    = (const int*)d_in[25];
    const int* dpi0    = (const int*)d_in[26];
    const int* dpi1    = (const int*)d_in[27];
    const int* dpi2    = (const int*)d_in[28];
    const int* upi0    = (const int*)d_in[29];
    const int* upi1    = (const int*)d_in[30];
    const int* upi2    = (const int*)d_in[31];

    float* outy = (float*)d_out;        // [16,20480,3] = 983040 fp32
    float* outz = outy + 983040;        // [16,256]     = 4096  fp32

    char* ws  = (char*)d_ws;
    float* zf = (float*)ws;                    // 16 KB fp32 z accumulator
    float* Wf = (float*)(ws + 16384);          // fp32 dec_W2^T (1728 floats)
    bf16* P   = (bf16*)(ws + 32768);           // 20.97M bf16 elems (42 MB)
    bf16* Q   = P + 20971520;                  // 20.97M bf16 elems (42 MB)

    // ---- prologue
    zero_k<<<16, 256, 0, stream>>>(zf, 4096);
    wcvt_k<<<7, 256, 0, stream>>>(decW2, Wf);

    // ---- encoder
    conv_k<float, 3, 64, 4, 32, true><<<dim3(640, 16), 256, 0, stream>>>(x, idx0, encW0, encb0, P, 20480, 20480);
    pool_k<<<2560, 256, 0, stream>>>(P, dpi0, dpw0, Q, 5120, 20480, 64);
    conv_k<bf16, 64, 128, 4, 16, true><<<dim3(320, 16), 256, 0, stream>>>(Q, idx1, encW1, encb1, P, 5120, 5120);
    pool_k<<<1280, 256, 0, stream>>>(P, dpi1, dpw1, Q, 1280, 5120, 128);
    conv_k<bf16, 128, 256, 4, 8, true><<<dim3(160, 16), 256, 0, stream>>>(Q, idx2, encW2, encb2, P, 1280, 1280);
    pool_k<<<640, 256, 0, stream>>>(P, dpi2, dpw2, Q, 320, 1280, 256);

    // ---- latent
    zacc_k<<<320, 256, 0, stream>>>(Q, Wz, zf);
    zfin_k<<<16, 256, 0, stream>>>(zf, bz, outz);
    dproj_k<<<320, 256, 0, stream>>>(zf, Wp, bp, P);   // d -> P [16,320,256] (as [16,81920])

    // ---- decoder
    pool_k<<<2560, 256, 0, stream>>>(P, upi0, upw0, Q, 1280, 320, 256);
    conv_k<bf16, 256, 128, 2, 4, true><<<dim3(320, 16), 256, 0, stream>>>(Q, idx2, decW0, decb0, P, 1280, 1280);
    pool_k<<<5120, 256, 0, stream>>>(P, upi1, upw1, Q, 5120, 1280, 128);
    conv_k<bf16, 128, 64, 2, 8, true><<<dim3(640, 16), 256, 0, stream>>>(Q, idx1, decW1, decb1, P, 5120, 5120);
    pool_k<<<10240, 256, 0, stream>>>(P, upi2, upw2, Q, 20480, 5120, 64);
    dec2_k<<<1280, 256, 0, stream>>>(Q, idx0, Wf, decb2, outy);
}

// Round 3
// 605.918 us; speedup vs baseline: 6.3327x; 6.3327x over previous
//
#include <hip/hip_runtime.h>
#include <hip/hip_bf16.h>
#include <math.h>

typedef __hip_bfloat16 bf16;
typedef short bf16x8 __attribute__((ext_vector_type(8)));
typedef float f32x4 __attribute__((ext_vector_type(4)));

// ---------- bf16 helpers (bit-level, RNE pack) ----------
__device__ __forceinline__ float bfbits2f(unsigned int u) {
    union { unsigned int i; float f; } c; c.i = u << 16; return c.f;
}
__device__ __forceinline__ float b2f(const bf16 v) {
    return __bfloat162float(v);
}
__device__ __forceinline__ unsigned short f2bbits(float f) {
    unsigned int x = __float_as_uint(f);
    x += 0x7fffu + ((x >> 16) & 1u);   // round-to-nearest-even
    return (unsigned short)(x >> 16);
}
__device__ __forceinline__ void unpack8(const uint4 v, float* f) {
    f[0]=bfbits2f(v.x & 0xffffu); f[1]=bfbits2f(v.x >> 16);
    f[2]=bfbits2f(v.y & 0xffffu); f[3]=bfbits2f(v.y >> 16);
    f[4]=bfbits2f(v.z & 0xffffu); f[5]=bfbits2f(v.z >> 16);
    f[6]=bfbits2f(v.w & 0xffffu); f[7]=bfbits2f(v.w >> 16);
}
__device__ __forceinline__ float ldx(const float* p) { return *p; }
__device__ __forceinline__ float ldx(const bf16* p)  { return b2f(*p); }

// ---------- tiny utility kernels ----------
__global__ void zero_k(float* p, int n) {
    int e = blockIdx.x * 256 + threadIdx.x;
    if (e < n) p[e] = 0.f;
}

// pack fp32 W[K][COUT] -> bf16 MFMA B-fragment layout:
// elem offset = ((kt2*NT + nt)*64 + lane)*8 + j  holds  W[kt2*32 + (lane>>4)*8 + j][nt*16 + (lane&15)]
__global__ void pack_k(const float* __restrict__ W, bf16* __restrict__ o,
                       const int K, const int COUT, const int NT, const int KP32) {
    const int e = blockIdx.x * 256 + threadIdx.x;
    const int total = KP32 * NT * 512;
    if (e >= total) return;
    const int j    = e & 7;
    const int lane = (e >> 3) & 63;
    const int rest = e >> 9;
    const int nt   = rest % NT;
    const int kt2  = rest / NT;
    const int k = kt2 * 32 + ((lane >> 4) << 3) + j;
    const int n = nt * 16 + (lane & 15);
    float v = (k < K && n < COUT) ? W[(size_t)k * COUT + n] : 0.f;
    union { unsigned short u; bf16 h; } c; c.u = f2bbits(v);
    o[e] = c.h;
}

// ---------- MFMA spiral conv ----------
// out[b,v,co] = sum_{s,ci} x[b, idx[v,s], ci] * W[s*CIN+ci, co] + bias ; optional ELU
// Block = 256 thr = 4 waves; 64 rows (= b*V+v) per block, wave w owns rows [w*16, w*16+16).
template<typename XT, typename OT, int CIN, int COUT, bool ELU>
__global__ __launch_bounds__(256) void mconv_k(
    const XT* __restrict__ x, const int* __restrict__ idx,
    const bf16* __restrict__ Wpk, const float* __restrict__ bias,
    OT* __restrict__ out, const int V, const int Vin)
{
    constexpr int K    = 9 * CIN;
    constexpr int KC   = (CIN >= 64) ? 64 : 32;   // k-chunk staged in LDS
    constexpr int NKC  = (K + KC - 1) / KC;
    constexpr int KS   = KC / 32;                 // MFMA k-steps per chunk
    constexpr int NT   = (COUT + 15) / 16;        // 16-col tiles
    constexpr int ROWB = KC * 2;                  // LDS bytes per row
    constexpr int SWZ  = (KC == 64) ? 7 : 3;      // XOR-swizzle rows (T2 / G4)

    __shared__ __align__(16) char alds[2][64 * ROWB];

    const int t  = threadIdx.x;
    const int w  = t >> 6;
    const int l  = t & 63;
    const int r0 = blockIdx.x * 64;
    const int b  = r0 / V;
    const int v0 = r0 - b * V;     // block's 64 rows stay within one batch (V % 64 == 0)

    f32x4 acc[NT];
    #pragma unroll
    for (int nt = 0; nt < NT; ++nt) acc[nt] = (f32x4){0.f, 0.f, 0.f, 0.f};

    // ---- stage chunk 0
    if constexpr (CIN >= 64) {
        const int srow = t >> 2, u2 = t & 3;     // 64 rows x 4 x 32B
        const int src = idx[(v0 + srow) * 9];    // s = 0 for chunk 0
        const XT* gp = x + ((size_t)b * Vin + src) * CIN + u2 * 16;
        const uint4 a0 = *(const uint4*)gp;
        const uint4 a1 = *(const uint4*)(gp + 8);
        char* wb = alds[0] + srow * ROWB;
        const int m = (srow & 7) << 4;
        *(uint4*)(wb + ((u2 * 32) ^ m))      = a0;
        *(uint4*)(wb + ((u2 * 32 + 16) ^ m)) = a1;
    } else {
        // CIN==3: K=27 padded to 32, single chunk, scalar staging
        for (int e = t; e < 64 * 32; e += 256) {
            const int row = e >> 5, k = e & 31;
            unsigned short hv = 0;
            if (k < K) {
                const int s = k / CIN, ci = k - s * CIN;
                const int src = idx[(v0 + row) * 9 + s];
                hv = f2bbits(ldx(x + ((size_t)b * Vin + src) * CIN + ci));
            }
            const int m2 = (row & 3) << 4;
            *(unsigned short*)(alds[0] + row * 64 + ((k * 2) ^ m2)) = hv;
        }
    }
    __syncthreads();

    const int rl = (w << 4) + (l & 15);      // this lane's A row
    const int rm = (rl & SWZ) << 4;
    const bf16x8* wpb = (const bf16x8*)Wpk;

    uint4 n0, n1;
    for (int kt = 0; kt < NKC; ++kt) {
        const bool hn = (kt + 1 < NKC);
        // T14: issue next chunk's global loads before compute
        if constexpr (CIN >= 64) {
            if (hn) {
                const int srow = t >> 2, u2 = t & 3;
                const int kn = kt + 1;
                const int s   = (kn * 64) / CIN;
                const int ci0 = (kn * 64) - s * CIN;
                const int src = idx[(v0 + srow) * 9 + s];
                const XT* gp = x + ((size_t)b * Vin + src) * CIN + ci0 + u2 * 16;
                n0 = *(const uint4*)gp;
                n1 = *(const uint4*)(gp + 8);
            }
        }
        // compute current chunk
        const char* ab = alds[kt & 1] + rl * ROWB;
        #pragma unroll
        for (int ks = 0; ks < KS; ++ks) {
            union { uint4 u; bf16x8 v; } af;
            af.u = *(const uint4*)(ab + ((ks * 64 + ((l >> 4) << 4)) ^ rm));
            const size_t wbase = ((size_t)(kt * KS + ks) * NT) * 64 + l;
            #pragma unroll
            for (int nt = 0; nt < NT; ++nt) {
                const bf16x8 bfv = wpb[wbase + (size_t)nt * 64];
                acc[nt] = __builtin_amdgcn_mfma_f32_16x16x32_bf16(af.v, bfv, acc[nt], 0, 0, 0);
            }
        }
        // write next chunk into the other LDS buffer
        if constexpr (CIN >= 64) {
            if (hn) {
                const int srow = t >> 2, u2 = t & 3;
                char* wb = alds[(kt + 1) & 1] + srow * ROWB;
                const int m = (srow & 7) << 4;
                *(uint4*)(wb + ((u2 * 32) ^ m))      = n0;
                *(uint4*)(wb + ((u2 * 32 + 16) ^ m)) = n1;
            }
        }
        __syncthreads();
    }

    // ---- epilogue: bias + ELU + store (D: col=lane&15, row=(lane>>4)*4+rr)
    const int colg = l & 15;
    const int rg   = (l >> 4) << 2;
    #pragma unroll
    for (int nt = 0; nt < NT; ++nt) {
        const int n = nt * 16 + colg;
        if constexpr (COUT < 16) { if (n >= COUT) continue; }
        const float bv = bias[n];
        #pragma unroll
        for (int rr = 0; rr < 4; ++rr) {
            float a = acc[nt][rr] + bv;
            if constexpr (ELU) a = a > 0.f ? a : (__expf(a) - 1.f);
            const size_t o = (size_t)(r0 + (w << 4) + rg + rr) * COUT + n;
            if constexpr (__is_same(OT, float)) {
                out[o] = a;
            } else {
                union { unsigned short u; bf16 h; } c; c.u = f2bbits(a);
                out[o] = c.h;
            }
        }
    }
}

// ---------- pool: out[b,vo,c] = sum_k w[vo,k] * in[b, idx[vo,k], c] ----------
__global__ __launch_bounds__(256) void pool_k(
    const bf16* __restrict__ in, const int* __restrict__ idx,
    const float* __restrict__ w, bf16* __restrict__ out,
    const int Vout, const int Vin, const int C)
{
    const int nC8 = C >> 3;
    const long long total = (long long)16 * Vout * nC8;
    const long long gid = (long long)blockIdx.x * 256 + threadIdx.x;
    if (gid >= total) return;
    const int c8 = (int)(gid % nC8);
    const long long bv = gid / nC8;
    const int vo = (int)(bv % Vout);
    const int b  = (int)(bv / Vout);

    float r[8];
    #pragma unroll
    for (int u = 0; u < 8; ++u) r[u] = 0.f;
    #pragma unroll
    for (int jj = 0; jj < 3; ++jj) {
        const int src = idx[vo * 3 + jj];
        const float ww = w[vo * 3 + jj];
        const uint4 xv = *(const uint4*)(in + ((size_t)b * Vin + src) * C + c8 * 8);
        float f[8]; unpack8(xv, f);
        #pragma unroll
        for (int u = 0; u < 8; ++u) r[u] += ww * f[u];
    }
    uint4 st;
    st.x = f2bbits(r[0]) | ((unsigned)f2bbits(r[1]) << 16);
    st.y = f2bbits(r[2]) | ((unsigned)f2bbits(r[3]) << 16);
    st.z = f2bbits(r[4]) | ((unsigned)f2bbits(r[5]) << 16);
    st.w = f2bbits(r[6]) | ((unsigned)f2bbits(r[7]) << 16);
    *(uint4*)(out + ((size_t)b * Vout + vo) * C + c8 * 8) = st;
}

// ---------- z = F[16,81920] @ Wz[81920,256] (partial sums via atomics) ----------
__global__ __launch_bounds__(256) void zacc_k(
    const bf16* __restrict__ F, const float* __restrict__ Wz, float* __restrict__ zf)
{
    const int j  = threadIdx.x;          // output col
    const int i0 = blockIdx.x * 256;     // K-chunk
    float acc[16];
    #pragma unroll
    for (int b = 0; b < 16; ++b) acc[b] = 0.f;
    for (int i = i0; i < i0 + 256; i += 8) {
        float w[8];
        #pragma unroll
        for (int u = 0; u < 8; ++u) w[u] = Wz[(size_t)(i + u) * 256 + j];
        #pragma unroll
        for (int b = 0; b < 16; ++b) {
            const uint4 fv = *(const uint4*)(F + (size_t)b * 81920 + i);
            float f[8]; unpack8(fv, f);
            #pragma unroll
            for (int u = 0; u < 8; ++u) acc[b] += f[u] * w[u];
        }
    }
    #pragma unroll
    for (int b = 0; b < 16; ++b) atomicAdd(&zf[b * 256 + j], acc[b]);
}

// add bias, keep fp32 copy for decoder, emit fp32 z output
__global__ void zfin_k(float* __restrict__ zf, const float* __restrict__ bz,
                       float* __restrict__ outz)
{
    int e = blockIdx.x * 256 + threadIdx.x;  // 4096
    int j = e & 255;
    float v = zf[e] + bz[j];
    zf[e] = v;
    outz[e] = v;
}

// ---------- d[b,j] = sum_k z[b,k] * Wp[k,j] + bp[j] ----------
__global__ __launch_bounds__(256) void dproj_k(
    const float* __restrict__ zf, const float* __restrict__ Wp,
    const float* __restrict__ bp, bf16* __restrict__ d)
{
    __shared__ float zl[256][16];   // [k][b]
    const int t = threadIdx.x;
    #pragma unroll
    for (int b = 0; b < 16; ++b) zl[t][b] = zf[b * 256 + t];
    __syncthreads();
    const size_t j = (size_t)blockIdx.x * 256 + t;
    const float bpv = bp[j];
    float acc[16];
    #pragma unroll
    for (int b = 0; b < 16; ++b) acc[b] = bpv;
    for (int k = 0; k < 256; ++k) {
        const float w = Wp[(size_t)k * 81920 + j];
        #pragma unroll
        for (int b = 0; b < 16; ++b) acc[b] += zl[k][b] * w;
    }
    #pragma unroll
    for (int b = 0; b < 16; ++b) {
        union { unsigned short u; bf16 h; } c; c.u = f2bbits(acc[b]);
        d[(size_t)b * 81920 + j] = c.h;
    }
}

extern "C" void kernel_launch(void* const* d_in, const int* in_sizes, int n_in,
                              void* d_out, int out_size, void* d_ws, size_t ws_size,
                              hipStream_t stream) {
    (void)in_sizes; (void)n_in; (void)out_size; (void)ws_size;
    const float* x     = (const float*)d_in[0];
    const float* encW0 = (const float*)d_in[1];
    const float* encb0 = (const float*)d_in[2];
    const float* encW1 = (const float*)d_in[3];
    const float* encb1 = (const float*)d_in[4];
    const float* encW2 = (const float*)d_in[5];
    const float* encb2 = (const float*)d_in[6];
    const float* Wz    = (const float*)d_in[7];
    const float* bz    = (const float*)d_in[8];
    const float* Wp    = (const float*)d_in[9];
    const float* bp    = (const float*)d_in[10];
    const float* decW0 = (const float*)d_in[11];
    const float* decb0 = (const float*)d_in[12];
    const float* decW1 = (const float*)d_in[13];
    const float* decb1 = (const float*)d_in[14];
    const float* decW2 = (const float*)d_in[15];
    const float* decb2 = (const float*)d_in[16];
    const float* dpw0  = (const float*)d_in[17];
    const float* dpw1  = (const float*)d_in[18];
    const float* dpw2  = (const float*)d_in[19];
    const float* upw0  = (const float*)d_in[20];
    const float* upw1  = (const float*)d_in[21];
    const float* upw2  = (const float*)d_in[22];
    const int* idx0    = (const int*)d_in[23];
    const int* idx1    = (const int*)d_in[24];
    const int* idx2    = (const int*)d_in[25];
    const int* dpi0    = (const int*)d_in[26];
    const int* dpi1    = (const int*)d_in[27];
    const int* dpi2    = (const int*)d_in[28];
    const int* upi0    = (const int*)d_in[29];
    const int* upi1    = (const int*)d_in[30];
    const int* upi2    = (const int*)d_in[31];

    float* outy = (float*)d_out;        // [16,20480,3]
    float* outz = outy + 983040;        // [16,256]

    // ws layout (proven 84MB+32KB footprint):
    //  [0,16K)   zf fp32
    //  P = ws+32K : 20,971,520 bf16  (max use 21.0M only at enc0-out; <=10.5M after)
    //  Q = P+21M  : 20,971,520 bf16  (max 21.0M only at upool2-out)
    //  Wbig = Q+10,485,760 elems (1.44MB): packed enc0,enc1,enc2,dec0,dec1 weights.
    //         Q never exceeds 10,485,760 elems before upool2; upool2 clobbers Wbig
    //         AFTER dec1 consumed it.
    //  dec2pk = P+10,485,760 elems (18KB): packed just-in-time after dec1 (P<=5.24M then).
    char* ws  = (char*)d_ws;
    float* zf = (float*)ws;
    bf16* P   = (bf16*)(ws + 32768);
    bf16* Q   = P + 20971520;
    bf16* Wbig   = Q + 10485760;
    bf16* dec2pk = P + 10485760;
    bf16* pk_e0 = Wbig;                 //   2048
    bf16* pk_e1 = Wbig + 2048;          //  73728
    bf16* pk_e2 = Wbig + 75776;         // 294912
    bf16* pk_d0 = Wbig + 370688;        // 294912
    bf16* pk_d1 = Wbig + 665600;        //  73728

    // ---- prologue: zero z accumulator, pack weights to MFMA fragment layout
    zero_k<<<16, 256, 0, stream>>>(zf, 4096);
    pack_k<<<8,    256, 0, stream>>>(encW0, pk_e0,   27,  64,  4,  1);
    pack_k<<<288,  256, 0, stream>>>(encW1, pk_e1,  576, 128,  8, 18);
    pack_k<<<1152, 256, 0, stream>>>(encW2, pk_e2, 1152, 256, 16, 36);
    pack_k<<<1152, 256, 0, stream>>>(decW0, pk_d0, 2304, 128,  8, 72);
    pack_k<<<288,  256, 0, stream>>>(decW1, pk_d1, 1152,  64,  4, 36);

    // ---- encoder
    mconv_k<float, bf16, 3, 64, true><<<5120, 256, 0, stream>>>(x, idx0, pk_e0, encb0, P, 20480, 20480);
    pool_k<<<2560, 256, 0, stream>>>(P, dpi0, dpw0, Q, 5120, 20480, 64);
    mconv_k<bf16, bf16, 64, 128, true><<<1280, 256, 0, stream>>>(Q, idx1, pk_e1, encb1, P, 5120, 5120);
    pool_k<<<1280, 256, 0, stream>>>(P, dpi1, dpw1, Q, 1280, 5120, 128);
    mconv_k<bf16, bf16, 128, 256, true><<<320, 256, 0, stream>>>(Q, idx2, pk_e2, encb2, P, 1280, 1280);
    pool_k<<<640, 256, 0, stream>>>(P, dpi2, dpw2, Q, 320, 1280, 256);

    // ---- latent
    zacc_k<<<320, 256, 0, stream>>>(Q, Wz, zf);
    zfin_k<<<16, 256, 0, stream>>>(zf, bz, outz);
    dproj_k<<<320, 256, 0, stream>>>(zf, Wp, bp, P);   // d -> P [16,320,256]

    // ---- decoder
    pool_k<<<2560, 256, 0, stream>>>(P, upi0, upw0, Q, 1280, 320, 256);
    mconv_k<bf16, bf16, 256, 128, true><<<320, 256, 0, stream>>>(Q, idx2, pk_d0, decb0, P, 1280, 1280);
    pool_k<<<5120, 256, 0, stream>>>(P, upi1, upw1, Q, 5120, 1280, 128);
    mconv_k<bf16, bf16, 128, 64, true><<<1280, 256, 0, stream>>>(Q, idx1, pk_d1, decb1, P, 5120, 5120);
    pack_k<<<36, 256, 0, stream>>>(decW2, dec2pk, 576, 3, 1, 18);
    pool_k<<<10240, 256, 0, stream>>>(P, upi2, upw2, Q, 20480, 5120, 64);
    mconv_k<bf16, float, 64, 3, false><<<5120, 256, 0, stream>>>(Q, idx0, dec2pk, decb2, outy, 20480, 20480);
}